// Round 1
// 494.907 us; speedup vs baseline: 1.0530x; 1.0530x over previous
//
#include <hip/hip_runtime.h>

#define Bn 128
#define Sn 512
#define Hn 1024
#define Ln 4

typedef float nfloat4 __attribute__((ext_vector_type(4)));

__device__ __forceinline__ float sigmoidf_(float x) { return 1.0f / (1.0f + __expf(-x)); }

// ---------------- K1: lengths[b] = count(x[b,:] > 0) ----------------
__global__ __launch_bounds__(128) void len_kernel(const int* __restrict__ x, int* __restrict__ lengths) {
  const int b = blockIdx.x, t = threadIdx.x;
  int4 v = ((const int4*)x)[b * 128 + t];
  int c = (v.x > 0) + (v.y > 0) + (v.z > 0) + (v.w > 0);
  for (int off = 32; off > 0; off >>= 1) c += __shfl_down(c, off);
  __shared__ int tmp[2];
  if ((t & 63) == 0) tmp[t >> 6] = c;
  __syncthreads();
  if (t == 0) lengths[b] = tmp[0] + tmp[1];
}

// ------- K2: stable descending argsort rank, sorted first tokens, bs_last -------
__global__ __launch_bounds__(128) void sort_kernel(const int* __restrict__ x, const int* __restrict__ lengths,
                                                   int* __restrict__ rank, int* __restrict__ tok_sorted,
                                                   int* __restrict__ bs_last) {
  __shared__ int sl[128];
  __shared__ int cnt;
  const int b = threadIdx.x;
  const int len = lengths[b];
  sl[b] = len;
  if (b == 0) cnt = 0;
  __syncthreads();
  int r = 0;
  for (int b2 = 0; b2 < 128; b2++) {
    int l2 = sl[b2];
    r += (l2 > len) || (l2 == len && b2 < b);
  }
  rank[b] = r;                 // unsort_idx[b] = position of original row b in sorted order
  tok_sorted[r] = x[b * Sn];   // x[sorted_idx[r], 0]
  if (len >= Sn) atomicAdd(&cnt, 1);
  __syncthreads();
  if (b == 0) bs_last[0] = cnt;
}

// ---------------- K3: split-K GEMM for gates i,g,o (f skipped: f*c0 == 0) ----------------
// grid = 32 m-tiles x 8 k-chunks = 256 blocks, 256 threads (4 waves).
// Layer 0: xt == emb and tok != nullptr -> rows gathered via tok_sorted (gather kernel fused).
// thread owns 4 consecutive rows r and 12 gate columns (4 m x {i,g,o}).
// partials[kc][q][m][r], q in {0:i,1:g,2:o}
__global__ __launch_bounds__(256) void gemm_kernel(const float* __restrict__ xt,
                                                   const int* __restrict__ tok,
                                                   const float* __restrict__ Wl,
                                                   float* __restrict__ part) {
  __shared__ float xtT[32][132];  // [kk][r], stride 132 keeps 16B alignment for b128 reads
  __shared__ float Ws[32][96];    // [kk][q*32 + mloc]
  __shared__ int sTok[128];
  const int t = threadIdx.x;
  const int mtile = blockIdx.x & 31;
  const int kc = blockIdx.x >> 5;
  const int rg = t & 31;
  const int msub = t >> 5;     // 0..7 -> m_loc = msub*4..+3
  const int k0 = kc * 128;
  const int kv4 = (t & 7) * 4;

  if (tok != nullptr) {        // uniform branch; layer 0 only
    if (t < 128) sTok[t] = tok[t];
    __syncthreads();
  }
  const float* xrow[4];
#pragma unroll
  for (int i = 0; i < 4; i++) {
    const int r = i * 32 + (t >> 3);
    const int row = (tok != nullptr) ? sTok[r] : r;
    xrow[i] = xt + (size_t)row * 1024;
  }

  float acc[3][4][4];
#pragma unroll
  for (int q = 0; q < 3; q++)
#pragma unroll
    for (int mm = 0; mm < 4; mm++)
#pragma unroll
      for (int rr = 0; rr < 4; rr++) acc[q][mm][rr] = 0.0f;

  float4 xreg[4], wreg[3];
  // prologue: load tile 0 into registers
  {
#pragma unroll
    for (int i = 0; i < 4; i++) xreg[i] = *(const float4*)&xrow[i][k0 + kv4];
#pragma unroll
    for (int i = 0; i < 3; i++) {
      int jj = i * 32 + (t >> 3);
      int q = jj >> 5, mloc = jj & 31;
      int qoff = (q == 0) ? 0 : ((q == 1) ? 2048 : 3072);  // gate rows: i, g, o
      wreg[i] = *(const float4*)&Wl[(size_t)(qoff + mtile * 32 + mloc) * 1024 + k0 + kv4];
    }
  }

#pragma unroll
  for (int tile = 0; tile < 4; tile++) {
    __syncthreads();
    // registers -> LDS (transposed)
#pragma unroll
    for (int i = 0; i < 4; i++) {
      const int r = i * 32 + (t >> 3);
      xtT[kv4 + 0][r] = xreg[i].x;
      xtT[kv4 + 1][r] = xreg[i].y;
      xtT[kv4 + 2][r] = xreg[i].z;
      xtT[kv4 + 3][r] = xreg[i].w;
    }
#pragma unroll
    for (int i = 0; i < 3; i++) {
      const int jj = i * 32 + (t >> 3);
      Ws[kv4 + 0][jj] = wreg[i].x;
      Ws[kv4 + 1][jj] = wreg[i].y;
      Ws[kv4 + 2][jj] = wreg[i].z;
      Ws[kv4 + 3][jj] = wreg[i].w;
    }
    // prefetch next tile while computing this one
    float4 xnxt[4], wnxt[3];
    if (tile < 3) {
      const int kt = k0 + (tile + 1) * 32;
#pragma unroll
      for (int i = 0; i < 4; i++) xnxt[i] = *(const float4*)&xrow[i][kt + kv4];
#pragma unroll
      for (int i = 0; i < 3; i++) {
        int jj = i * 32 + (t >> 3);
        int q = jj >> 5, mloc = jj & 31;
        int qoff = (q == 0) ? 0 : ((q == 1) ? 2048 : 3072);
        wnxt[i] = *(const float4*)&Wl[(size_t)(qoff + mtile * 32 + mloc) * 1024 + kt + kv4];
      }
    }
    __syncthreads();
#pragma unroll
    for (int kk = 0; kk < 32; kk++) {
      const float4 xv = *(const float4*)&xtT[kk][rg * 4];
      const float4 w0 = *(const float4*)&Ws[kk][msub * 4];
      const float4 w1 = *(const float4*)&Ws[kk][32 + msub * 4];
      const float4 w2 = *(const float4*)&Ws[kk][64 + msub * 4];
      const float xa[4] = {xv.x, xv.y, xv.z, xv.w};
      const float wv[3][4] = {{w0.x, w0.y, w0.z, w0.w},
                              {w1.x, w1.y, w1.z, w1.w},
                              {w2.x, w2.y, w2.z, w2.w}};
#pragma unroll
      for (int q = 0; q < 3; q++)
#pragma unroll
        for (int mm = 0; mm < 4; mm++)
#pragma unroll
          for (int rr = 0; rr < 4; rr++)
            acc[q][mm][rr] = fmaf(wv[q][mm], xa[rr], acc[q][mm][rr]);
    }
    if (tile < 3) {
#pragma unroll
      for (int i = 0; i < 4; i++) xreg[i] = xnxt[i];
#pragma unroll
      for (int i = 0; i < 3; i++) wreg[i] = wnxt[i];
    }
  }

  const int mbase = mtile * 32 + msub * 4;
#pragma unroll
  for (int q = 0; q < 3; q++)
#pragma unroll
    for (int mm = 0; mm < 4; mm++) {
      float4 v = make_float4(acc[q][mm][0], acc[q][mm][1], acc[q][mm][2], acc[q][mm][3]);
      *(float4*)&part[(((size_t)kc * 3 + q) * 1024 + (mbase + mm)) * 128 + rg * 4] = v;
    }
}

// ---------------- K4: reduce partials + biases, activations, states ----------------
// grid = 256 blocks (4 m each), 128 threads (thread = one sorted row r).
// Spreads the 12.6 MB partial reduction over all 256 CUs (was 64).
__global__ __launch_bounds__(128) void act_kernel(const float* __restrict__ part,
                                                  const float* __restrict__ bih,
                                                  const float* __restrict__ bhh,
                                                  const int* __restrict__ bs_last,
                                                  float* __restrict__ xt_out,
                                                  float* __restrict__ sh,
                                                  float* __restrict__ sc) {
  const int r = threadIdx.x;          // 0..127
  const int m0 = blockIdx.x * 4;
  const int bs = bs_last[0];
  float hv[4], cv[4];
#pragma unroll
  for (int mm = 0; mm < 4; mm++) {
    const int m = m0 + mm;
    float si = 0.f, sg = 0.f, so = 0.f;
#pragma unroll
    for (int kc = 0; kc < 8; kc++) {
      const float* p = part + (((size_t)kc * 3) * 1024 + m) * 128 + r;
      si += p[0];
      sg += p[(size_t)1024 * 128];
      so += p[(size_t)2048 * 128];
    }
    si += bih[m] + bhh[m];
    sg += bih[2048 + m] + bhh[2048 + m];
    so += bih[3072 + m] + bhh[3072 + m];
    const float c = sigmoidf_(si) * tanhf(sg);
    const float h = sigmoidf_(so) * tanhf(c);
    hv[mm] = h;
    cv[mm] = c;
  }
  const float msk = (r < bs) ? 1.0f : 0.0f;
  *(float4*)&xt_out[(size_t)r * 1024 + m0] = make_float4(hv[0], hv[1], hv[2], hv[3]);
  *(float4*)&sh[(size_t)r * 1024 + m0] =
      make_float4(msk * hv[0], msk * hv[1], msk * hv[2], msk * hv[3]);
  *(float4*)&sc[(size_t)r * 1024 + m0] =
      make_float4(msk * cv[0], msk * cv[1], msk * cv[2], msk * cv[3]);
}

// ---------------- K5: output[t,b,:] = (t < len[b]) ? h_final_sorted[rank[b],:] : 0 ----------------
// grid = 128 b x 8 t-chunks (64 t each). h row loaded ONCE per block into registers,
// then 64 x 4KB contiguous nontemporal stores. Kills the per-(t,b) hfin re-reads.
__global__ __launch_bounds__(256) void bcast_kernel(const float* __restrict__ hfin,
                                                    const int* __restrict__ lengths,
                                                    const int* __restrict__ rank,
                                                    float* __restrict__ out) {
  const int b = blockIdx.x & 127;
  const int c = blockIdx.x >> 7;      // 0..7
  const int len = lengths[b];
  const int t0 = c * 64;
  nfloat4 v = (nfloat4)0.0f;
  if (t0 < len) v = ((const nfloat4*)hfin)[rank[b] * 256 + threadIdx.x];
  int valid = len - t0;
  valid = valid < 0 ? 0 : (valid > 64 ? 64 : valid);
  nfloat4* p = (nfloat4*)out + ((size_t)t0 * 128 + b) * 256 + threadIdx.x;
  for (int i = 0; i < valid; i++) {
    __builtin_nontemporal_store(v, p);
    p += 32768;                        // one t step = 128*1024 floats
  }
  const nfloat4 z = (nfloat4)0.0f;
  for (int i = valid; i < 64; i++) {
    __builtin_nontemporal_store(z, p);
    p += 32768;
  }
}

extern "C" void kernel_launch(void* const* d_in, const int* in_sizes, int n_in,
                              void* d_out, int out_size, void* d_ws, size_t ws_size,
                              hipStream_t stream) {
  const int* x = (const int*)d_in[0];
  const float* emb = (const float*)d_in[1];
  const float* W_ih = (const float*)d_in[2];
  // d_in[3] = W_hh: NEVER multiplied (h0 == 0); only b_hh is added.
  const float* b_ih = (const float*)d_in[4];
  const float* b_hh = (const float*)d_in[5];

  float* out = (float*)d_out;
  float* sh = out + (size_t)Sn * Bn * Hn;   // state_h [L,B,H]
  float* sc = sh + (size_t)Ln * Bn * Hn;    // state_c [L,B,H]
  float* part = out;                        // 12 MB GEMM-partial scratch inside the
                                            // output region; overwritten by bcast later.

  char* ws = (char*)d_ws;
  int* lengths = (int*)ws;                  // [128]
  int* rank = lengths + 128;                // [128]
  int* tok_sorted = rank + 128;             // [128]
  int* bs_last = tok_sorted + 128;          // [1]
  float* xtA = (float*)(ws + 4096);         // [128,1024]
  float* xtB = xtA + 128 * 1024;            // [128,1024]

  len_kernel<<<128, 128, 0, stream>>>(x, lengths);
  sort_kernel<<<1, 128, 0, stream>>>(x, lengths, rank, tok_sorted, bs_last);

  // layer 0 consumes emb rows gathered via tok_sorted directly (no gather kernel)
  float* bufs[2] = {xtA, xtB};
  const float* xin = emb;
  const int* tokp = tok_sorted;
  for (int l = 0; l < Ln; l++) {
    gemm_kernel<<<256, 256, 0, stream>>>(xin, tokp, W_ih + (size_t)l * 4 * Hn * Hn, part);
    act_kernel<<<256, 128, 0, stream>>>(part, b_ih + l * 4 * Hn, b_hh + l * 4 * Hn, bs_last,
                                        bufs[l & 1], sh + (size_t)l * Bn * Hn,
                                        sc + (size_t)l * Bn * Hn);
    xin = bufs[l & 1];
    tokp = nullptr;
  }
  // after the loop, xin == xtB holds the top-layer h (sorted order)
  bcast_kernel<<<1024, 256, 0, stream>>>(xin, lengths, rank, out);
}